// Round 3
// baseline (3833.315 us; speedup 1.0000x reference)
//
#include <hip/hip_runtime.h>
#include <cstdint>
#include <cstddef>

// ---------------------------------------------------------------------------
// AttentionLSTM, per-step launch design (no grid barriers, no atomics).
// Per step t:
//   k_attn: per-n WG: M=h·A2 (scale, softmax) -> attn[n,h]=sum_k A2[n,h,k]w_k
//   k_step: act = [h | x_t | attn] @ W2 + b  (K=2560 f16 MFMA GEMM),
//           gates, c update, h write, out write.
// Cross-XCD visibility via kernel boundaries on the stream (HSA semantics).
// ---------------------------------------------------------------------------

typedef _Float16 f16;
typedef _Float16 v8h  __attribute__((ext_vector_type(8)));
typedef float    v4f  __attribute__((ext_vector_type(4)));
typedef int      v4i  __attribute__((ext_vector_type(4)));

#define NN 256
#define TT 128
#define DD 512
#define HH 1024
#define FH 4096
#define K2 2560      // H + D + H (h | x | attn)

// ---- workspace layout (bytes), total ~30.5 MiB ----
#define OFF_C    ((size_t)0)                                 // c fp32      1 MB
#define OFF_H16  (OFF_C   + (size_t)NN*HH*4)                 // h f16 dbuf  1 MB
#define OFF_A2   (OFF_H16 + (size_t)2*NN*HH*2)               // A2 f16 [n][h][16]  8.4 MB
#define OFF_ATT  (OFF_A2  + (size_t)NN*HH*16*2)              // attn f16    0.5 MB
#define OFF_W2T  (OFF_ATT + (size_t)NN*HH*2)                 // W2T f16 [4096][2560] 21 MB

#define AS1(p) ((const __attribute__((address_space(1))) void*)(p))
#define AS3(p) ((__attribute__((address_space(3))) void*)(p))

// ---------------------------------------------------------------------------
// per (n,h): h0=c0=mean(A[n,h,:,:]), A2 f16 cast
__global__ __launch_bounds__(256) void k_prepA(
    const float* __restrict__ A, float* c_ws, f16* h0buf, f16* __restrict__ A2)
{
  const int idx = blockIdx.x*256 + threadIdx.x;     // (n,h), 262144 total
  const v4f* ap = (const v4f*)(A + (size_t)idx*16);
  v4f a0 = ap[0], a1 = ap[1], a2 = ap[2], a3 = ap[3];
  float fa[16];
#pragma unroll
  for (int i = 0; i < 4; ++i) { fa[i]=a0[i]; fa[4+i]=a1[i]; fa[8+i]=a2[i]; fa[12+i]=a3[i]; }
  float s = 0.f;
#pragma unroll
  for (int i = 0; i < 16; ++i) s += fa[i];
  const float h0 = s * (1.f/16.f);
  c_ws[idx] = h0;
  h0buf[idx] = (f16)h0;
  v8h lo, hi;
#pragma unroll
  for (int i = 0; i < 8; ++i) { lo[i] = (f16)fa[i]; hi[i] = (f16)fa[8+i]; }
  *(v8h*)(A2 + (size_t)idx*16)     = lo;
  *(v8h*)(A2 + (size_t)idx*16 + 8) = hi;
}

// out[c][ooff+r] = (f16) in[r][c]   (LDS tile transpose, f32 -> f16)
__global__ __launch_bounds__(256) void k_transT(
    const float* __restrict__ in, int R, int C, f16* __restrict__ outp, int ostride, int ooff)
{
  __shared__ float tile[32][33];
  const int tx = threadIdx.x & 31, ty = threadIdx.x >> 5;
  const int c0 = blockIdx.x << 5, r0 = blockIdx.y << 5;
#pragma unroll
  for (int i = 0; i < 4; ++i)
    tile[ty + 8*i][tx] = in[(size_t)(r0 + ty + 8*i)*C + c0 + tx];
  __syncthreads();
#pragma unroll
  for (int i = 0; i < 4; ++i)
    outp[(size_t)(c0 + ty + 8*i)*ostride + ooff + r0 + tx] = (f16)tile[tx][ty + 8*i];
}

// ---------------------------------------------------------------------------
// k_attn: one WG (256 thr) per sample n.
// thread t owns h in {t, t+256, t+512, t+768}; A2 rows cached in regs.
__global__ __launch_bounds__(256) void k_attn(
    const f16* __restrict__ hcur, const f16* __restrict__ A2, f16* __restrict__ attn16)
{
  __shared__ float red[256][17];     // padded: conflict-free
  __shared__ float Msm[16];
  __shared__ f16 attn_lds[1024];
  const int tid = threadIdx.x, n = blockIdx.x;

  v8h a2[4][2];
  float hv[4];
#pragma unroll
  for (int i = 0; i < 4; ++i) {
    const int h = tid + 256*i;
    hv[i] = (float)hcur[(size_t)n*HH + h];
    const v8h* p = (const v8h*)(A2 + ((size_t)n*HH + h)*16);
    a2[i][0] = p[0]; a2[i][1] = p[1];
  }
  float mp[16];
#pragma unroll
  for (int k = 0; k < 16; ++k) mp[k] = 0.f;
#pragma unroll
  for (int i = 0; i < 4; ++i)
#pragma unroll
    for (int k = 0; k < 16; ++k)
      mp[k] += hv[i] * (float)a2[i][k>>3][k&7];
#pragma unroll
  for (int k = 0; k < 16; ++k) red[tid][k] = mp[k];
  __syncthreads();
  if (tid < 64) {
#pragma unroll
    for (int k = 0; k < 16; ++k)
      red[tid][k] += red[tid+64][k] + red[tid+128][k] + red[tid+192][k];
  }
  __syncthreads();
  if (tid < 16) {
    float m = 0.f;
    for (int j = 0; j < 64; ++j) m += red[j][tid];
    Msm[tid] = m * 0.03125f;         // * 1/sqrt(H)
  }
  __syncthreads();
  float w[16];
  {
    float mx = Msm[0];
#pragma unroll
    for (int k = 1; k < 16; ++k) mx = fmaxf(mx, Msm[k]);
    float s = 0.f;
#pragma unroll
    for (int k = 0; k < 16; ++k) { w[k] = __expf(Msm[k] - mx); s += w[k]; }
    const float inv = 1.f / s;
#pragma unroll
    for (int k = 0; k < 16; ++k) w[k] *= inv;
  }
#pragma unroll
  for (int i = 0; i < 4; ++i) {
    float a = 0.f;
#pragma unroll
    for (int k = 0; k < 16; ++k) a += w[k] * (float)a2[i][k>>3][k&7];
    attn_lds[tid + 256*i] = (f16)a;
  }
  __syncthreads();
  if (tid < 128)
    ((v4i*)(attn16 + (size_t)n*HH))[tid] = ((v4i*)attn_lds)[tid];
}

// ---------------------------------------------------------------------------
// k_step: 256 WGs = 4 rg (64 rows) x 64 cg (4 gates x 16 cols).
// 4 waves x (16 rows x 64 cols); A direct-to-regs, B via global_load_lds.
__global__ __launch_bounds__(256) void k_step(
    const float* __restrict__ x, const f16* __restrict__ W2T,
    const f16* __restrict__ attn16, const float* __restrict__ bb,
    float* __restrict__ c_ws, const f16* __restrict__ hcur,
    f16* __restrict__ hnxt, float* __restrict__ out, int t)
{
  __shared__ __align__(16) f16 Blds[2][16384];   // [64 col][256 k] x2 = 64 KB
  const int tid = threadIdx.x, lane = tid & 63, wv = tid >> 6;
  const int l15 = lane & 15, l4 = lane >> 4;
  const int bid = blockIdx.x;
  const int rg = bid >> 6, cg = bid & 63;        // partners (same cg) share XCD (mod 8)
  const int n0 = rg << 6;
  const int hc0 = cg << 4;
  const int wrow = wv << 4;

  v4f acc[4];
#pragma unroll
  for (int g = 0; g < 4; ++g) acc[g] = v4f{0.f,0.f,0.f,0.f};

  auto stageB = [&](int sl) {                    // stage 64col x 256k slab
    f16* base = Blds[sl & 1];
    const int Kb = sl << 8;
#pragma unroll
    for (int rnd = 0; rnd < 8; ++rnd) {
      const int s = tid + (rnd << 8);
      const int col = s >> 5, ksp = s & 31;
      const int kslog = (ksp & 24) | ((ksp ^ col) & 7);   // src-side XOR swizzle
      const int j = ((col >> 4) << 10) + hc0 + (col & 15);
      const f16* src = W2T + (size_t)j*K2 + Kb + kslog*8;
      __builtin_amdgcn_global_load_lds(AS1(src), AS3(base + s*8), 16, 0, 0);
    }
  };

  auto loadA = [&](int c, v8h& o0, v8h& o1) {    // A-operand, k-chunk c of 64
    const int n = n0 + wrow + l15;
#pragma unroll
    for (int s = 0; s < 2; ++s) {
      const int k = c*64 + s*32 + (l4 << 3);
      v8h v;
      if (c < 16) {
        v = *(const v8h*)(hcur + (size_t)n*HH + k);
      } else if (c < 24) {
        const float* xp = x + ((size_t)n*TT + t)*DD + (k - HH);
        v4f f0 = *(const v4f*)xp, f1 = *(const v4f*)(xp + 4);
#pragma unroll
        for (int e = 0; e < 4; ++e) { v[e] = (f16)f0[e]; v[4+e] = (f16)f1[e]; }
      } else {
        v = *(const v8h*)(attn16 + (size_t)n*HH + (k - 1536));
      }
      if (s) o1 = v; else o0 = v;
    }
  };

  auto compute = [&](int c, v8h a0, v8h a1) {
    const f16* Bb = Blds[(c >> 2) & 1];
#pragma unroll
    for (int s = 0; s < 2; ++s) {
      const v8h av = s ? a1 : a0;
#pragma unroll
      for (int cf = 0; cf < 4; ++cf) {
        const int col = cf*16 + l15;
        const int phys = ((s << 2) | l4) ^ (col & 7);     // read-side XOR (matches src)
        const v8h bf = *(const v8h*)(Bb + col*256 + (c & 3)*64 + phys*8);
        acc[cf] = __builtin_amdgcn_mfma_f32_16x16x32_f16(av, bf, acc[cf], 0, 0, 0);
      }
    }
  };

  stageB(0);
  v8h ra0[3], ra1[3];
  loadA(0, ra0[0], ra1[0]);
  loadA(1, ra0[1], ra1[1]);
  __syncthreads();
  stageB(1);
#pragma unroll
  for (int c = 0; c < 40; ++c) {
    if (c + 2 < 40) loadA(c + 2, ra0[(c + 2) % 3], ra1[(c + 2) % 3]);
    compute(c, ra0[c % 3], ra1[c % 3]);
    if ((c & 3) == 3 && c < 39) {
      __syncthreads();                            // drains vmcnt before reuse
      const int nsl = (c >> 2) + 2;
      if (nsl <= 9) stageB(nsl);
    }
  }

  // epilogue: i/f/o/g in-lane (cf == gate)
  const int hcol = hc0 + l15;
  float bg[4];
#pragma unroll
  for (int g = 0; g < 4; ++g) bg[g] = bb[(g << 10) + hcol];
#pragma unroll
  for (int reg = 0; reg < 4; ++reg) {
    const int n = n0 + wrow + (l4 << 2) + reg;
    const float ai = acc[0][reg] + bg[0];
    const float af = acc[1][reg] + bg[1];
    const float ao = acc[2][reg] + bg[2];
    const float ag = acc[3][reg] + bg[3];
    const float iv = 1.f/(1.f + __expf(-ai));
    const float fv = 1.f/(1.f + __expf(-af));
    const float ov = 1.f/(1.f + __expf(-ao));
    const float eg = __expf(-2.f*fabsf(ag));
    const float gv = copysignf((1.f - eg)/(1.f + eg), ag);
    const size_t ci = (size_t)n*HH + hcol;
    const float cn = fv*c_ws[ci] + iv*gv;
    c_ws[ci] = cn;
    const float ec = __expf(-2.f*fabsf(cn));
    const float hv = ov * copysignf((1.f - ec)/(1.f + ec), cn);
    out[((size_t)n*TT + t)*HH + hcol] = hv;
    hnxt[ci] = (f16)hv;
  }
}

// ---------------------------------------------------------------------------
extern "C" void kernel_launch(void* const* d_in, const int* in_sizes, int n_in,
                              void* d_out, int out_size, void* d_ws, size_t ws_size,
                              hipStream_t stream)
{
  const float* x  = (const float*)d_in[0];
  const float* A  = (const float*)d_in[1];
  const float* Wx = (const float*)d_in[2];
  const float* Wh = (const float*)d_in[3];
  const float* Wa = (const float*)d_in[4];
  const float* bb = (const float*)d_in[5];
  float* out = (float*)d_out;
  char* ws = (char*)d_ws;

  float* c_ws   = (float*)(ws + OFF_C);
  f16*   h16    = (f16*)(ws + OFF_H16);
  f16*   A2     = (f16*)(ws + OFF_A2);
  f16*   attn16 = (f16*)(ws + OFF_ATT);
  f16*   W2T    = (f16*)(ws + OFF_W2T);

  // prep: h0/c0 + A2 cast; W2T[j][k] = concat rows {Wh, Wx, Wattn} transposed
  k_prepA<<<dim3(1024), dim3(256), 0, stream>>>(A, c_ws, h16, A2);
  k_transT<<<dim3(128, 32), dim3(256), 0, stream>>>(Wh, 1024, 4096, W2T, K2, 0);
  k_transT<<<dim3(128, 16), dim3(256), 0, stream>>>(Wx,  512, 4096, W2T, K2, 1024);
  k_transT<<<dim3(128, 32), dim3(256), 0, stream>>>(Wa, 1024, 4096, W2T, K2, 1536);

  for (int t = 0; t < TT; ++t) {
    const f16* hcur = h16 + (size_t)(t & 1)*NN*HH;
    f16*       hnxt = h16 + (size_t)((t + 1) & 1)*NN*HH;
    k_attn<<<dim3(NN), dim3(256), 0, stream>>>(hcur, A2, attn16);
    k_step<<<dim3(256), dim3(256), 0, stream>>>(
        x, W2T, attn16, bb, c_ws, hcur, hnxt, out, t);
  }
}